// Round 1
// baseline (141.194 us; speedup 1.0000x reference)
//
#include <hip/hip_runtime.h>

#define NB 4
#define CH 256
#define CL 512
#define HH 64
#define HWD 64
#define LHD 32
#define LWD 32
#define PLANE (HH*HWD)      // 4096
#define LPLANE (LHD*LWD)    // 1024
#define NPIX (NB*PLANE)     // 16384
#define G 8
#define CSUB (CH/G)         // 32

// ---------------- Kernel 1: BN statistics -> scale/shift ----------------
__global__ void bn_stats_kernel(const float* __restrict__ high,
                                const float* __restrict__ gamma,
                                const float* __restrict__ beta,
                                float* __restrict__ scale,
                                float* __restrict__ shift) {
    int c = blockIdx.x;          // 256 channels
    int tid = threadIdx.x;       // 256 threads
    float s = 0.f, s2 = 0.f;
    for (int b = 0; b < NB; ++b) {
        const float* p = high + ((size_t)(b * CH + c)) * PLANE;
        for (int i = tid; i < PLANE; i += 256) {
            float v = p[i];
            s += v; s2 += v * v;
        }
    }
    __shared__ float sm1[4], sm2[4];
    int lane = tid & 63, wid = tid >> 6;
    #pragma unroll
    for (int off = 32; off > 0; off >>= 1) {
        s  += __shfl_down(s, off);
        s2 += __shfl_down(s2, off);
    }
    if (lane == 0) { sm1[wid] = s; sm2[wid] = s2; }
    __syncthreads();
    if (tid == 0) {
        float S  = sm1[0] + sm1[1] + sm1[2] + sm1[3];
        float S2 = sm2[0] + sm2[1] + sm2[2] + sm2[3];
        const float invN = 1.f / (float)(NB * PLANE);
        float mean = S * invN;
        float var  = S2 * invN - mean * mean;
        float sc = gamma[c] * rsqrtf(var + 1e-5f);
        scale[c] = sc;
        shift[c] = beta[c] - mean * sc;
    }
}

// ---------------- Kernel 2: down = affine(avgpool2x2(high)) ----------------
__global__ void down_kernel(const float* __restrict__ high,
                            const float* __restrict__ scale,
                            const float* __restrict__ shift,
                            float* __restrict__ down) {
    int idx = blockIdx.x * 256 + threadIdx.x;   // NB*CH*LPLANE = 1048576
    int lx = idx & 31;
    int ly = (idx >> 5) & 31;
    int bc = idx >> 10;            // b*CH + c
    int c = bc & (CH - 1);
    const float* p = high + (size_t)bc * PLANE + (ly * 2) * HWD + lx * 2;
    float avg = 0.25f * (p[0] + p[1] + p[HWD] + p[HWD + 1]);
    down[idx] = avg * scale[c] + shift[c];
}

// ------- Kernel 3: partial scores, channel-split into G groups -------
__global__ void scores_partial_kernel(const float* __restrict__ high,
                                      const float* __restrict__ scale,
                                      const float* __restrict__ shift,
                                      const float* __restrict__ down,
                                      float* __restrict__ part) {
    int idx = blockIdx.x * 256 + threadIdx.x;   // [0, G*NPIX) = 131072
    int pix = idx & (NPIX - 1);
    int g = idx >> 14;
    int x = pix & 63, y = (pix >> 6) & 63, b = pix >> 12;
    int ly = y >> 1, lx = x >> 1;

    float sc9[9];
    #pragma unroll
    for (int k = 0; k < 9; ++k) sc9[k] = 0.f;

    for (int ci = 0; ci < CSUB; ++ci) {
        int c = g * CSUB + ci;
        const float* hp = high + ((size_t)(b * CH + c)) * PLANE;
        const float* dp = down + ((size_t)(b * CH + c)) * LPLANE;
        float sck = scale[c], shf = shift[c];
        float hv[3][3], dv[3][3];
        #pragma unroll
        for (int dy = 0; dy < 3; ++dy) {
            int yy = y + dy - 1;
            int lyy = ly + dy - 1;
            #pragma unroll
            for (int dx = 0; dx < 3; ++dx) {
                int xx = x + dx - 1;
                int lxx = lx + dx - 1;
                hv[dy][dx] = (yy >= 0 && yy < HH && xx >= 0 && xx < HWD)
                             ? hp[yy * HWD + xx] * sck + shf : 0.f;
                dv[dy][dx] = (lyy >= 0 && lyy < LHD && lxx >= 0 && lxx < LWD)
                             ? dp[lyy * LWD + lxx] : 0.f;
            }
        }
        #pragma unroll
        for (int k = 0; k < 9; ++k) {
            float d = hv[k / 3][k % 3] - dv[k / 3][k % 3];
            sc9[k] += d * d;
        }
    }
    float* pp = part + ((size_t)(g * NB + b) * 9) * PLANE + (pix & (PLANE - 1));
    #pragma unroll
    for (int k = 0; k < 9; ++k) pp[k * PLANE] = sc9[k];
}

// ---------------- Kernel 4: sum partials + bias -> softmax -> att ----------------
__global__ void softmax_kernel(const float* __restrict__ part,
                               const float* __restrict__ bias,
                               float* __restrict__ att) {
    int idx = blockIdx.x * 256 + threadIdx.x;   // [0, NPIX)
    int b = idx >> 12;
    int yx = idx & (PLANE - 1);
    float sc9[9];
    #pragma unroll
    for (int k = 0; k < 9; ++k) sc9[k] = bias[k];
    for (int g = 0; g < G; ++g) {
        const float* pp = part + ((size_t)(g * NB + b) * 9) * PLANE + yx;
        #pragma unroll
        for (int k = 0; k < 9; ++k) sc9[k] += pp[k * PLANE];
    }
    float m = sc9[0];
    #pragma unroll
    for (int k = 1; k < 9; ++k) m = fmaxf(m, sc9[k]);
    float sum = 0.f;
    #pragma unroll
    for (int k = 0; k < 9; ++k) { sc9[k] = __expf(sc9[k] - m); sum += sc9[k]; }
    float inv = 1.f / sum;
    float* ap = att + (size_t)b * 9 * PLANE + yx;
    #pragma unroll
    for (int k = 0; k < 9; ++k) ap[k * PLANE] = sc9[k] * inv;
}

// ---------------- Kernel 5: weighted aggregation -> out ----------------
__global__ void out_kernel(const float* __restrict__ low,
                           const float* __restrict__ att,
                           float* __restrict__ out) {
    int idx = blockIdx.x * 256 + threadIdx.x;   // NB*CL*PLANE = 8388608
    int yx = idx & (PLANE - 1);
    int x = idx & 63, y = (idx >> 6) & 63;
    int bl = idx >> 12;          // b*CL + l
    int l = bl & (CL - 1);
    int b = bl >> 9;
    const float* ap = att + (size_t)b * 9 * PLANE + yx;
    float a[9];
    #pragma unroll
    for (int k = 0; k < 9; ++k) a[k] = ap[k * PLANE];
    int ly = y >> 1, lx = x >> 1;
    const float* lp = low + (size_t)(b * CL + l) * LPLANE;
    float acc = 0.f;
    #pragma unroll
    for (int dy = 0; dy < 3; ++dy) {
        int lyy = ly + dy - 1;
        #pragma unroll
        for (int dx = 0; dx < 3; ++dx) {
            int lxx = lx + dx - 1;
            float v = (lyy >= 0 && lyy < LHD && lxx >= 0 && lxx < LWD)
                      ? lp[lyy * LWD + lxx] : 0.f;
            acc += a[dy * 3 + dx] * v;
        }
    }
    out[idx] = acc;
}

extern "C" void kernel_launch(void* const* d_in, const int* in_sizes, int n_in,
                              void* d_out, int out_size, void* d_ws, size_t ws_size,
                              hipStream_t stream) {
    const float* low   = (const float*)d_in[0];
    const float* high  = (const float*)d_in[1];
    const float* gamma = (const float*)d_in[2];
    const float* beta  = (const float*)d_in[3];
    const float* bias  = (const float*)d_in[4];
    float* out = (float*)d_out;

    float* ws = (float*)d_ws;
    float* scale = ws;                               // 256
    float* shift = ws + 256;                         // 256
    float* down  = ws + 512;                         // NB*CH*LPLANE = 1048576
    float* part  = down + (size_t)NB * CH * LPLANE;  // G*NB*9*PLANE = 1179648
    float* att   = part + (size_t)G * NB * 9 * PLANE; // 147456

    bn_stats_kernel<<<CH, 256, 0, stream>>>(high, gamma, beta, scale, shift);
    down_kernel<<<(NB * CH * LPLANE) / 256, 256, 0, stream>>>(high, scale, shift, down);
    scores_partial_kernel<<<(G * NPIX) / 256, 256, 0, stream>>>(high, scale, shift, down, part);
    softmax_kernel<<<NPIX / 256, 256, 0, stream>>>(part, bias, att);
    out_kernel<<<(NB * CL * PLANE) / 256, 256, 0, stream>>>(low, att, out);
}

// Round 2
// 51.832 us; speedup vs baseline: 2.7241x; 2.7241x over previous
//
#include <hip/hip_runtime.h>

#define NB 4
#define CH 256
#define CL 512
#define HH 64
#define HWD 64
#define LHD 32
#define LWD 32
#define PLANE (HH*HWD)      // 4096
#define LPLANE (LHD*LWD)    // 1024
#define NPIX (NB*PLANE)     // 16384

// ---------------- Kernel 1a: BN partial sums (block = (c, b)) ----------------
__global__ void bn_stage1_kernel(const float* __restrict__ high,
                                 float* __restrict__ partS,
                                 float* __restrict__ partS2) {
    int bid = blockIdx.x;            // c*4 + b, 1024 blocks
    int b = bid & 3;
    int c = bid >> 2;
    int tid = threadIdx.x;           // 256
    const float* p = high + ((size_t)(b * CH + c)) * PLANE;
    float s = 0.f, s2 = 0.f;
    #pragma unroll
    for (int i = 0; i < 4; ++i) {
        float4 v = *(const float4*)(p + (i * 256 + tid) * 4);
        s  += v.x + v.y + v.z + v.w;
        s2 += v.x * v.x + v.y * v.y + v.z * v.z + v.w * v.w;
    }
    __shared__ float sm1[4], sm2[4];
    int lane = tid & 63, wid = tid >> 6;
    #pragma unroll
    for (int off = 32; off > 0; off >>= 1) {
        s  += __shfl_down(s, off);
        s2 += __shfl_down(s2, off);
    }
    if (lane == 0) { sm1[wid] = s; sm2[wid] = s2; }
    __syncthreads();
    if (tid == 0) {
        partS[bid]  = sm1[0] + sm1[1] + sm1[2] + sm1[3];
        partS2[bid] = sm2[0] + sm2[1] + sm2[2] + sm2[3];
    }
}

// ---------------- Kernel 1b: finalize scale/shift ----------------
__global__ void bn_stage2_kernel(const float* __restrict__ partS,
                                 const float* __restrict__ partS2,
                                 const float* __restrict__ gamma,
                                 const float* __restrict__ beta,
                                 float* __restrict__ scale,
                                 float* __restrict__ shift) {
    int c = threadIdx.x;             // 256
    float S  = partS[c*4+0] + partS[c*4+1] + partS[c*4+2] + partS[c*4+3];
    float S2 = partS2[c*4+0] + partS2[c*4+1] + partS2[c*4+2] + partS2[c*4+3];
    const float invN = 1.f / (float)(NB * PLANE);
    float mean = S * invN;
    float var  = S2 * invN - mean * mean;
    float sc = gamma[c] * rsqrtf(var + 1e-5f);
    scale[c] = sc;
    shift[c] = beta[c] - mean * sc;
}

// ------- Kernel 2: channels-last transpose + affine + pooled down -------
// Block: (b, row-pair r, 64-channel chunk). LDS tile[2][64][65].
__global__ void transpose_kernel(const float* __restrict__ high,
                                 const float* __restrict__ scale,
                                 const float* __restrict__ shift,
                                 float* __restrict__ Ht,
                                 float* __restrict__ Dt) {
    int bid = blockIdx.x;            // 4*32*4 = 512
    int cchunk = bid & 3;
    int r = (bid >> 2) & 31;
    int b = bid >> 7;
    int c0 = cchunk * 64;
    __shared__ float tile[2][64][65];
    int tid = threadIdx.x;           // 256

    // load phase: 128 (c,row) rows x 64 x, float4 per lane-group
    int xg = tid & 15;               // x in groups of 4
    int jr = tid >> 4;               // 0..15
    #pragma unroll
    for (int i = 0; i < 8; ++i) {
        int j = i * 16 + jr;         // 0..127
        int cl = j >> 1, row = j & 1;
        const float* p = high + (((size_t)(b * CH + c0 + cl) * HH + (2 * r + row)) * HWD) + xg * 4;
        float4 v = *(const float4*)p;
        tile[row][cl][xg * 4 + 0] = v.x;
        tile[row][cl][xg * 4 + 1] = v.y;
        tile[row][cl][xg * 4 + 2] = v.z;
        tile[row][cl][xg * 4 + 3] = v.w;
    }
    __syncthreads();

    int c = tid & 63;
    float sc = scale[c0 + c], sh = shift[c0 + c];

    // Ht store: lanes along c -> contiguous 256B
    int pg = tid >> 6;               // 0..3
    #pragma unroll
    for (int i = 0; i < 32; ++i) {
        int pix = i * 4 + pg;        // 0..127
        int row = pix >> 6, x = pix & 63;
        float v = tile[row][c][x] * sc + sh;
        Ht[(((size_t)(b * HH + 2 * r + row) * HWD) + x) * CH + c0 + c] = v;
    }

    // Dt store: 2x2 pooled
    int lxg = tid >> 6;              // 0..3
    #pragma unroll
    for (int i = 0; i < 8; ++i) {
        int lx = i * 4 + lxg;        // 0..31
        float sum = tile[0][c][2*lx] + tile[0][c][2*lx+1]
                  + tile[1][c][2*lx] + tile[1][c][2*lx+1];
        Dt[(((size_t)(b * LHD + r) * LWD) + lx) * CH + c0 + c] = 0.25f * sum * sc + sh;
    }
}

// ------- Kernel 3: wave-per-pixel scores + softmax -> att -------
__global__ void scores_softmax_kernel(const float* __restrict__ Ht,
                                      const float* __restrict__ Dt,
                                      const float* __restrict__ bias,
                                      float* __restrict__ att) {
    int tid = threadIdx.x;
    int lane = tid & 63, wid = tid >> 6;
    int pix = blockIdx.x * 4 + wid;      // [0, NPIX)
    int b = pix >> 12;
    int yx = pix & (PLANE - 1);
    int y = yx >> 6, x = yx & 63;
    const float* Hb = Ht + (size_t)b * PLANE * CH;
    const float* Db = Dt + (size_t)b * LPLANE * CH;
    int c4 = lane * 4;

    float acc[9];
    #pragma unroll
    for (int k = 0; k < 9; ++k) {
        int dy = k / 3, dx = k % 3;
        int yy = y + dy - 1, xx = x + dx - 1;
        float4 hv = make_float4(0.f, 0.f, 0.f, 0.f);
        if (yy >= 0 && yy < HH && xx >= 0 && xx < HWD)
            hv = *(const float4*)(Hb + ((size_t)((yy << 6) + xx)) * CH + c4);
        int qy = (y >> 1) + dy - 1, qx = (x >> 1) + dx - 1;
        float4 dv = make_float4(0.f, 0.f, 0.f, 0.f);
        if (qy >= 0 && qy < LHD && qx >= 0 && qx < LWD)
            dv = *(const float4*)(Db + ((size_t)((qy << 5) + qx)) * CH + c4);
        float dx0 = hv.x - dv.x, dx1 = hv.y - dv.y, dx2 = hv.z - dv.z, dx3 = hv.w - dv.w;
        acc[k] = dx0 * dx0 + dx1 * dx1 + dx2 * dx2 + dx3 * dx3;
    }
    // 64-lane butterfly reduce, all 9 accumulators
    #pragma unroll
    for (int off = 32; off > 0; off >>= 1) {
        #pragma unroll
        for (int k = 0; k < 9; ++k) acc[k] += __shfl_xor(acc[k], off);
    }
    if (lane == 0) {
        float e[9];
        float m = -1e30f;
        #pragma unroll
        for (int k = 0; k < 9; ++k) { e[k] = acc[k] + bias[k]; m = fmaxf(m, e[k]); }
        float sum = 0.f;
        #pragma unroll
        for (int k = 0; k < 9; ++k) { e[k] = __expf(e[k] - m); sum += e[k]; }
        float inv = 1.f / sum;
        float* ap = att + (size_t)b * 9 * PLANE + yx;
        #pragma unroll
        for (int k = 0; k < 9; ++k) ap[k * PLANE] = e[k] * inv;
    }
}

// ---------------- Kernel 4: out, 4 l-channels x 4 x-pixels per thread ----------------
__global__ void out_kernel(const float* __restrict__ low,
                           const float* __restrict__ att,
                           float* __restrict__ out) {
    int idx = blockIdx.x * 256 + threadIdx.x;   // 524288 threads
    int x4 = idx & 15;
    int y  = (idx >> 4) & 63;
    int l4 = (idx >> 10) & 127;
    int b  = idx >> 17;
    int x0 = x4 * 4;
    int l0 = l4 * 4;

    const float* ap = att + (size_t)b * 9 * PLANE + (y << 6) + x0;
    float a[9][4];
    #pragma unroll
    for (int k = 0; k < 9; ++k) {
        float4 v = *(const float4*)(ap + k * PLANE);
        a[k][0] = v.x; a[k][1] = v.y; a[k][2] = v.z; a[k][3] = v.w;
    }
    int ly = y >> 1;
    int lx0 = x4 * 2;
    #pragma unroll
    for (int li = 0; li < 4; ++li) {
        const float* lp = low + (size_t)(b * CL + l0 + li) * LPLANE;
        float lv[3][4];
        #pragma unroll
        for (int dy = 0; dy < 3; ++dy) {
            int lyy = ly + dy - 1;
            #pragma unroll
            for (int j = 0; j < 4; ++j) {
                int lxx = lx0 - 1 + j;
                lv[dy][j] = (lyy >= 0 && lyy < LHD && lxx >= 0 && lxx < LWD)
                            ? lp[lyy * LWD + lxx] : 0.f;
            }
        }
        float o[4];
        #pragma unroll
        for (int i = 0; i < 4; ++i) {
            float s = 0.f;
            #pragma unroll
            for (int k = 0; k < 9; ++k) {
                int dy = k / 3, dx = k % 3;
                s += a[k][i] * lv[dy][(i >> 1) + dx];
            }
            o[i] = s;
        }
        float4 ov = make_float4(o[0], o[1], o[2], o[3]);
        *(float4*)(out + ((size_t)(b * CL + l0 + li) * PLANE) + (y << 6) + x0) = ov;
    }
}

extern "C" void kernel_launch(void* const* d_in, const int* in_sizes, int n_in,
                              void* d_out, int out_size, void* d_ws, size_t ws_size,
                              hipStream_t stream) {
    const float* low   = (const float*)d_in[0];
    const float* high  = (const float*)d_in[1];
    const float* gamma = (const float*)d_in[2];
    const float* beta  = (const float*)d_in[3];
    const float* bias  = (const float*)d_in[4];
    float* out = (float*)d_out;

    float* ws = (float*)d_ws;
    float* partS  = ws;                       // 1024
    float* partS2 = partS + 1024;             // 1024
    float* scale  = partS2 + 1024;            // 256
    float* shift  = scale + 256;              // 256
    float* Ht     = shift + 256;              // 4*64*64*256 = 4194304
    float* Dt     = Ht + (size_t)NB * PLANE * CH;    // 4*32*32*256 = 1048576
    float* att    = Dt + (size_t)NB * LPLANE * CH;   // 4*9*4096 = 147456

    bn_stage1_kernel<<<1024, 256, 0, stream>>>(high, partS, partS2);
    bn_stage2_kernel<<<1, 256, 0, stream>>>(partS, partS2, gamma, beta, scale, shift);
    transpose_kernel<<<512, 256, 0, stream>>>(high, scale, shift, Ht, Dt);
    scores_softmax_kernel<<<NPIX / 4, 256, 0, stream>>>(Ht, Dt, bias, att);
    out_kernel<<<2048, 256, 0, stream>>>(low, att, out);
}